// Round 10
// baseline (231.933 us; speedup 1.0000x reference)
//
#include <hip/hip_runtime.h>
#include <hip/hip_bf16.h>
#include <math.h>

// Problem constants (B=1)
#define T_SEQ 4096
#define C_DIM 1024
#define N_HEADS 16
#define HEAD_D 64

typedef __bf16 bf16x8 __attribute__((ext_vector_type(8)));
typedef float f32x4 __attribute__((ext_vector_type(4)));

__device__ __forceinline__ unsigned int pack_bf16x2(float lo, float hi) {
  unsigned short a = __builtin_bit_cast(unsigned short, __float2bfloat16(lo));
  unsigned short b = __builtin_bit_cast(unsigned short, __float2bfloat16(hi));
  return (unsigned int)a | ((unsigned int)b << 16);
}

// Async global->LDS, 16B per lane, wave-uniform LDS base + lane*16.
__device__ __forceinline__ void load_lds16(const void* g, void* l) {
  __builtin_amdgcn_global_load_lds(
      (const __attribute__((address_space(1))) unsigned int*)g,
      (__attribute__((address_space(3))) unsigned int*)l, 16, 0, 0);
}

// Explicit drain of outstanding vector-memory ops (global_load_lds) —
// guarantees the pre-barrier vmcnt(0) the async staging protocol requires,
// independent of compiler alias analysis.
__device__ __forceinline__ void vm_drain() {
  asm volatile("s_waitcnt vmcnt(0)" ::: "memory");
}

// ---------------------------------------------------------------------------
// prep: x cast (blocks 0..2047) + w_qkv transpose (2048..2815) + w_out
// transpose (2816..3071). One launch.
// ---------------------------------------------------------------------------
__global__ __launch_bounds__(256) void prep_inputs(
    const float* __restrict__ x, const float* __restrict__ w_qkv,
    const float* __restrict__ w_out, unsigned int* __restrict__ xb,
    unsigned int* __restrict__ wqkvT, unsigned int* __restrict__ woutT) {
  __shared__ float tile[64][65];
  const int b = blockIdx.x;
  const int tid = threadIdx.x;

  if (b < 2048) {  // cast x -> bf16, 8 elems/thread
    const int i = b * 256 + tid;
    const float4 a = ((const float4*)x)[2 * i];
    const float4 c = ((const float4*)x)[2 * i + 1];
    uint4 r;
    r.x = pack_bf16x2(a.x, a.y);
    r.y = pack_bf16x2(a.z, a.w);
    r.z = pack_bf16x2(c.x, c.y);
    r.w = pack_bf16x2(c.z, c.w);
    ((uint4*)xb)[i] = r;
    return;
  }

  const float* W;
  unsigned int* WT;
  int N, bb;
  if (b < 2816) {
    W = w_qkv; WT = wqkvT; N = 3072; bb = b - 2048;
  } else {
    W = w_out; WT = woutT; N = 1024; bb = b - 2816;
  }
  const int K = 1024;
  const int n0 = (bb % (N / 64)) * 64, k0 = (bb / (N / 64)) * 64;
#pragma unroll
  for (int i = 0; i < 16; i++) {
    const int idx = i * 256 + tid;
    const int r = idx >> 6, c = idx & 63;  // r: k, c: n
    tile[r][c] = W[(size_t)(k0 + r) * N + n0 + c];
  }
  __syncthreads();
#pragma unroll
  for (int i = 0; i < 8; i++) {
    const int idx = i * 256 + tid;
    const int rn = idx >> 5, p = idx & 31;  // rn: n-row, p: k-pair
    WT[((size_t)(n0 + rn) * K + k0) / 2 + p] =
        pack_bf16x2(tile[2 * p][rn], tile[2 * p + 1][rn]);
  }
}

// ---------------------------------------------------------------------------
// bf16 MFMA GEMM (m97 structure): C[M][N] f32 = A[M][K]bf16 * Bt[N][K]bf16^T
// Tile 128x128, 4 waves 2x2. For the qkv projection.
// ---------------------------------------------------------------------------
__global__ __launch_bounds__(256) void gemm_bt_bf16(
    const unsigned short* __restrict__ A,   // [M][K]
    const unsigned short* __restrict__ Bt,  // [N][K]
    float* __restrict__ C, int M, int N, int K) {
  __shared__ __align__(16) unsigned short As[128 * 32];
  __shared__ __align__(16) unsigned short Bs[128 * 32];
  const int tid = threadIdx.x;
  const int w = tid >> 6, lane = tid & 63;
  const int quad = lane >> 4, l16 = lane & 15;
  const int bm = blockIdx.y * 128, bn = blockIdx.x * 128;
  const int mw = (w & 1) * 64, nw = (w >> 1) * 64;

  f32x4 acc[4][4];
#pragma unroll
  for (int mt = 0; mt < 4; mt++)
#pragma unroll
    for (int nt = 0; nt < 4; nt++) acc[mt][nt] = (f32x4){0.f, 0.f, 0.f, 0.f};

  const int crow = lane >> 2;
  const int cq = lane & 3;
  const unsigned short* Ab = A + (size_t)bm * K;
  const unsigned short* Bb = Bt + (size_t)bn * K;

  for (int k0 = 0; k0 < K; k0 += 32) {
#pragma unroll
    for (int i = 0; i < 2; i++) {
      const int c = w + i * 4;
      const int row = c * 16 + crow;
      load_lds16(Ab + (size_t)row * K + k0 + cq * 8, As + c * 512);
      load_lds16(Bb + (size_t)row * K + k0 + cq * 8, Bs + c * 512);
    }
    vm_drain();
    __syncthreads();

    bf16x8 af[4], bf[4];
#pragma unroll
    for (int mt = 0; mt < 4; mt++)
      af[mt] = __builtin_bit_cast(
          bf16x8, *(const int4*)(As + (mw + mt * 16 + l16) * 32 + quad * 8));
#pragma unroll
    for (int nt = 0; nt < 4; nt++)
      bf[nt] = __builtin_bit_cast(
          bf16x8, *(const int4*)(Bs + (nw + nt * 16 + l16) * 32 + quad * 8));
#pragma unroll
    for (int mt = 0; mt < 4; mt++)
#pragma unroll
      for (int nt = 0; nt < 4; nt++)
        acc[mt][nt] = __builtin_amdgcn_mfma_f32_16x16x32_bf16(
            af[mt], bf[nt], acc[mt][nt], 0, 0, 0);
    __syncthreads();
  }

#pragma unroll
  for (int mt = 0; mt < 4; mt++)
#pragma unroll
    for (int nt = 0; nt < 4; nt++)
#pragma unroll
      for (int reg = 0; reg < 4; reg++)
        C[(size_t)(bm + mw + mt * 16 + quad * 4 + reg) * N + bn + nw +
          nt * 16 + l16] = acc[mt][nt][reg];
}

// ---------------------------------------------------------------------------
// 64x64-tile GEMM for the out-projection: 1024 blocks -> 4/CU. fp32 out.
// ---------------------------------------------------------------------------
__global__ __launch_bounds__(256) void gemm_bt_bf16_64(
    const unsigned short* __restrict__ A,   // [M][K]
    const unsigned short* __restrict__ Bt,  // [N][K]
    float* __restrict__ C, int M, int N, int K) {
  __shared__ __align__(16) unsigned short As[64 * 32];
  __shared__ __align__(16) unsigned short Bs[64 * 32];
  const int tid = threadIdx.x;
  const int w = tid >> 6, lane = tid & 63;
  const int quad = lane >> 4, l16 = lane & 15;
  const int bm = blockIdx.y * 64, bn = blockIdx.x * 64;
  const int mw = (w & 1) * 32, nw = (w >> 1) * 32;

  f32x4 acc[2][2];
#pragma unroll
  for (int mt = 0; mt < 2; mt++)
#pragma unroll
    for (int nt = 0; nt < 2; nt++) acc[mt][nt] = (f32x4){0.f, 0.f, 0.f, 0.f};

  const unsigned short* Ab = A + (size_t)bm * K;
  const unsigned short* Bb = Bt + (size_t)bn * K;
  const int srow = w * 16 + (lane >> 2);
  const int scol = (lane & 3) * 8;

  for (int k0 = 0; k0 < K; k0 += 32) {
    load_lds16(Ab + (size_t)srow * K + k0 + scol, As + w * 512);
    load_lds16(Bb + (size_t)srow * K + k0 + scol, Bs + w * 512);
    vm_drain();
    __syncthreads();

    bf16x8 af[2], bf[2];
#pragma unroll
    for (int mt = 0; mt < 2; mt++)
      af[mt] = __builtin_bit_cast(
          bf16x8, *(const int4*)(As + (mw + mt * 16 + l16) * 32 + quad * 8));
#pragma unroll
    for (int nt = 0; nt < 2; nt++)
      bf[nt] = __builtin_bit_cast(
          bf16x8, *(const int4*)(Bs + (nw + nt * 16 + l16) * 32 + quad * 8));
#pragma unroll
    for (int mt = 0; mt < 2; mt++)
#pragma unroll
      for (int nt = 0; nt < 2; nt++)
        acc[mt][nt] = __builtin_amdgcn_mfma_f32_16x16x32_bf16(
            af[mt], bf[nt], acc[mt][nt], 0, 0, 0);
    __syncthreads();
  }

#pragma unroll
  for (int mt = 0; mt < 2; mt++)
#pragma unroll
    for (int nt = 0; nt < 2; nt++)
#pragma unroll
      for (int reg = 0; reg < 4; reg++)
        C[(size_t)(bm + mw + mt * 16 + quad * 4 + reg) * N + bn + nw +
          nt * 16 + l16] = acc[mt][nt][reg];
}

// ---------------------------------------------------------------------------
// RoPE + split to bf16: Qb[h][t][d] (PRE-SCALED by 0.125*log2(e) so that
// exp2(Q'.K) == exp(0.125*Q.K)), Kb[h][t][d], Vt[h][d][t] (transposed).
// Reads fp32 qkv (R8 dataflow).
// ---------------------------------------------------------------------------
__global__ __launch_bounds__(256) void rope_split_bf16(
    const float* __restrict__ qkv, unsigned short* __restrict__ Qb,
    unsigned short* __restrict__ Kb, unsigned short* __restrict__ Vt) {
  const int tb = blockIdx.x * 64;
  const int h = blockIdx.y;
  const int tid = threadIdx.x;

  const int j = tid & 31;
  const int r0 = tid >> 5;  // 0..7
  const float inv = powf(10000.0f, -(2.0f * (float)j) / 64.0f);
  const float QSCALE = 0.125f * 1.44269504089f;  // 1/sqrt(D) * log2(e)
  unsigned int* Qu = (unsigned int*)Qb;
  unsigned int* Ku = (unsigned int*)Kb;
#pragma unroll
  for (int rr = 0; rr < 8; rr++) {
    const int t = tb + r0 + rr * 8;
    float s, c;
    sincosf((float)t * inv, &s, &c);
    const float* base = qkv + (size_t)t * (3 * C_DIM) + h * HEAD_D + 2 * j;
    const float2 q2 = *(const float2*)(base);
    const float2 k2 = *(const float2*)(base + C_DIM);
    const float qe = (q2.x * c - q2.y * s) * QSCALE;
    const float qo = (q2.y * c + q2.x * s) * QSCALE;
    const float ke = k2.x * c - k2.y * s;
    const float ko = k2.y * c + k2.x * s;
    const size_t ridx = ((size_t)h * T_SEQ + t) * 32 + j;
    Qu[ridx] = pack_bf16x2(qe, qo);
    Ku[ridx] = pack_bf16x2(ke, ko);
  }

  __shared__ float vs[64][65];
#pragma unroll
  for (int i = 0; i < 16; i++) {
    const int idx = i * 256 + tid;
    const int r = idx >> 6, d = idx & 63;
    vs[r][d] = qkv[(size_t)(tb + r) * (3 * C_DIM) + 2 * C_DIM + h * HEAD_D + d];
  }
  __syncthreads();
  unsigned int* Vu = (unsigned int*)Vt;
#pragma unroll
  for (int i = 0; i < 8; i++) {
    const int idx = i * 256 + tid;
    const int d = idx >> 5, sp = idx & 31;
    Vu[((size_t)(h * HEAD_D + d)) * (T_SEQ / 2) + (tb >> 1) + sp] =
        pack_bf16x2(vs[2 * sp][d], vs[2 * sp + 1][d]);
  }
}

// ---------------------------------------------------------------------------
// Flash attention v4c': R8 protocol + hoisted lane-constant LDS addresses +
// EXPLICIT vmcnt(0) drains before both barriers (async-staging correctness is
// no longer at the mercy of compiler waitcnt policy). Operand-swapped MFMA
// (A=K -> S^T; A=V^T -> O^T), qt balance map, K dbuf + V single buffer, lsum
// via all-ones MFMA. LDS 33792 B -> 4 blocks/CU.
// ---------------------------------------------------------------------------
__global__ __launch_bounds__(256) void attn_mfma(
    const unsigned short* __restrict__ Qb, const unsigned short* __restrict__ Kb,
    const unsigned short* __restrict__ Vt, unsigned short* __restrict__ O) {
  const int b = blockIdx.x;
  const int rep = b >> 8;
  const int jj = b & 255;
  const int h = jj & 15;
  const int u = jj >> 4;
  const int qmap[4] = {u, 63 - u, 16 + u, 47 - u};
  const int qt = qmap[rep];

  const int tid = threadIdx.x;
  const int w = tid >> 6;
  const int lane = tid & 63;
  const int quad = lane >> 4;
  const int l16 = lane & 15;
  const int qb = qt * 64;
  const int qw = qb + w * 16;

  __shared__ __align__(16) unsigned short Ks[2][64 * 64];
  __shared__ __align__(16) unsigned short Vs[64 * 64];
  __shared__ __align__(16) unsigned short plds[4][16][72];  // [wave][q][s]

  const unsigned short* Kh = Kb + (size_t)h * T_SEQ * HEAD_D;
  const unsigned short* Vh = Vt + (size_t)h * HEAD_D * T_SEQ;

  // Q B-frags (persist): B[k=d][n=q]: q = l16, d = quad*8+j (+32 for ks=1)
  bf16x8 bq[2];
  {
    const unsigned short* qrow =
        Qb + ((size_t)h * T_SEQ + qw + l16) * HEAD_D + quad * 8;
#pragma unroll
    for (int ks = 0; ks < 2; ks++)
      bq[ks] = __builtin_bit_cast(bf16x8, *(const int4*)(qrow + ks * 32));
  }

  bf16x8 aones;
#pragma unroll
  for (int i = 0; i < 8; i++) aones[i] = (__bf16)1.0f;

  f32x4 o[4];
#pragma unroll
  for (int dt = 0; dt < 4; dt++) o[dt] = (f32x4){0.f, 0.f, 0.f, 0.f};
  f32x4 lacc = (f32x4){0.f, 0.f, 0.f, 0.f};

  // ---- hoisted lane-constant LDS read bases ----
  // key&7 == l16&7 (nt*16 ≡ 0 mod 8) and ((4+quad)^x)*8 == ((quad^x)*8)^32
  const int x7 = l16 & 7;
  const int o0 = (quad ^ x7) * 8;  // elements
  const int o1 = o0 ^ 32;
  const int rbase = l16 * 64;
  const unsigned short* k0a = Ks[0] + rbase + o0;
  const unsigned short* k0b = Ks[0] + rbase + o1;
  const unsigned short* k1a = Ks[1] + rbase + o0;
  const unsigned short* k1b = Ks[1] + rbase + o1;
  const unsigned short* va = Vs + rbase + o0;
  const unsigned short* vb = Vs + rbase + o1;
  unsigned short* pw = &plds[w][l16][quad * 4];        // writes: +nt*16
  const unsigned short* pr = &plds[w][l16][quad * 8];  // reads: +0, +32

  // ---- staging: running global pointers ----
  const int sr = tid >> 3;  // row 0..31 (+32 for second issue)
  const int sc = tid & 7;   // 16B chunk
  const int csoff = (sc ^ (sr & 7)) * 8;
  const unsigned short* kgrun = Kh + (size_t)sr * HEAD_D + csoff;
  const unsigned short* vgrun = Vh + (size_t)sr * T_SEQ + csoff;
  const int ntiles = qb / 64 + 1;

  // stage K tile 0
  load_lds16(kgrun, &Ks[0][w * 512]);
  load_lds16(kgrun + 2048, &Ks[0][(4 + w) * 512]);
  kgrun += 4096;

  for (int it = 0; it < ntiles; it++) {
    const int s0 = it * 64;
    const int cur = it & 1;
    // barrier1: K[cur] staged; prev iteration's V-phase reads complete
    vm_drain();
    __syncthreads();
    if (it + 1 < ntiles) {
      unsigned short* kd = &Ks[cur ^ 1][w * 512];
      load_lds16(kgrun, kd);
      load_lds16(kgrun + 2048, kd + 2048);
      kgrun += 4096;
    }
    load_lds16(vgrun, &Vs[w * 512]);
    load_lds16(vgrun + 32 * T_SEQ, &Vs[(4 + w) * 512]);
    vgrun += 64;

    const unsigned short* ka = cur ? k1a : k0a;
    const unsigned short* kc = cur ? k1b : k0b;

    // S^T = K Q^T; D-layout: key = nt*16 + quad*4 + reg, q = l16.
    f32x4 sv[4];
#pragma unroll
    for (int nt = 0; nt < 4; nt++) {
      const bf16x8 a0 =
          __builtin_bit_cast(bf16x8, *(const int4*)(ka + nt * 1024));
      const bf16x8 a1 =
          __builtin_bit_cast(bf16x8, *(const int4*)(kc + nt * 1024));
      f32x4 z = (f32x4){0.f, 0.f, 0.f, 0.f};
      z = __builtin_amdgcn_mfma_f32_16x16x32_bf16(a0, bq[0], z, 0, 0, 0);
      sv[nt] = __builtin_amdgcn_mfma_f32_16x16x32_bf16(a1, bq[1], z, 0, 0, 0);
    }

    // causal mask: only the diagonal tile is partial
    if (s0 == qb) {
      const int qg = qw + l16;
#pragma unroll
      for (int nt = 0; nt < 4; nt++)
#pragma unroll
        for (int reg = 0; reg < 4; reg++) {
          const int sg = s0 + nt * 16 + quad * 4 + reg;
          if (sg > qg) sv[nt][reg] = -1e30f;
        }
    }

    // p = 2^s, pack 4 consecutive keys -> b64 LDS write (P^T layout [q][s])
#pragma unroll
    for (int nt = 0; nt < 4; nt++) {
      float p0 = exp2f(sv[nt][0]), p1 = exp2f(sv[nt][1]);
      float p2 = exp2f(sv[nt][2]), p3 = exp2f(sv[nt][3]);
      uint2 pk;
      pk.x = pack_bf16x2(p0, p1);
      pk.y = pack_bf16x2(p2, p3);
      *(uint2*)(pw + nt * 16) = pk;
    }

    // B-frags for PV: B[k=s][n=q]
    bf16x8 bp[2];
    bp[0] = __builtin_bit_cast(bf16x8, *(const int4*)(pr));
    bp[1] = __builtin_bit_cast(bf16x8, *(const int4*)(pr + 32));

    // lsum via MFMA (ones-A): D[m][q] = sum_k P^T[k][q]
    lacc = __builtin_amdgcn_mfma_f32_16x16x32_bf16(aones, bp[0], lacc, 0, 0, 0);
    lacc = __builtin_amdgcn_mfma_f32_16x16x32_bf16(aones, bp[1], lacc, 0, 0, 0);

    // barrier2: V staged (QK+exp compute hid its latency)
    vm_drain();
    __syncthreads();

    // O^T += V^T P^T
#pragma unroll
    for (int dt = 0; dt < 4; dt++) {
      const bf16x8 a0 =
          __builtin_bit_cast(bf16x8, *(const int4*)(va + dt * 1024));
      const bf16x8 a1 =
          __builtin_bit_cast(bf16x8, *(const int4*)(vb + dt * 1024));
      o[dt] = __builtin_amdgcn_mfma_f32_16x16x32_bf16(a0, bp[0], o[dt], 0, 0, 0);
      o[dt] = __builtin_amdgcn_mfma_f32_16x16x32_bf16(a1, bp[1], o[dt], 0, 0, 0);
    }
  }

  // epilogue: lacc holds full key-sum for q = l16 (replicated) -> no shuffles
  const float invl = 1.0f / lacc[0];
  const int row = qw + l16;
#pragma unroll
  for (int dt = 0; dt < 4; dt++) {
    uint2 pk;
    pk.x = pack_bf16x2(o[dt][0] * invl, o[dt][1] * invl);
    pk.y = pack_bf16x2(o[dt][2] * invl, o[dt][3] * invl);
    *(uint2*)(O + (size_t)row * C_DIM + h * HEAD_D + dt * 16 + quad * 4) = pk;
  }
}

// ---------------------------------------------------------------------------
// Launch (R8 dataflow: fp32 qkv intermediate, rope does V transpose)
// ---------------------------------------------------------------------------
extern "C" void kernel_launch(void* const* d_in, const int* in_sizes, int n_in,
                              void* d_out, int out_size, void* d_ws,
                              size_t ws_size, hipStream_t stream) {
  const float* x = (const float*)d_in[0];      // [T][C]
  const float* w_qkv = (const float*)d_in[1];  // [C][3C]
  const float* w_out = (const float*)d_in[2];  // [C][C]
  float* out = (float*)d_out;                  // [T][C]

  char* ws = (char*)d_ws;
  // Workspace layout (88 MB peak):
  //   [0, 48MB):  qkv fp32 [T][3C]; reused later as attn_ob bf16 [T][C]
  //   [48,56MB):  Qb bf16 [H][T][D] (pre-scaled by 0.125*log2e)
  //   [56,64MB):  Kb bf16 [H][T][D]
  //   [64,72MB):  Vt bf16 [H][D][T]
  //   [72,80MB):  xb bf16 [T][C]
  //   [80,86MB):  wqkvT bf16 [3C][C]
  //   [86,88MB):  woutT bf16 [C][C]
  float* qkv = (float*)ws;
  unsigned short* Qb = (unsigned short*)(ws + (size_t)48 * 1024 * 1024);
  unsigned short* Kb = (unsigned short*)(ws + (size_t)56 * 1024 * 1024);
  unsigned short* Vt = (unsigned short*)(ws + (size_t)64 * 1024 * 1024);
  unsigned short* xb = (unsigned short*)(ws + (size_t)72 * 1024 * 1024);
  unsigned short* wqkvT = (unsigned short*)(ws + (size_t)80 * 1024 * 1024);
  unsigned short* woutT = (unsigned short*)(ws + (size_t)86 * 1024 * 1024);
  unsigned short* attn_ob = (unsigned short*)ws;  // reuse qkv space

  dim3 blk(256);

  // 0) fused cast + transposes
  prep_inputs<<<dim3(3072), blk, 0, stream>>>(
      x, w_qkv, w_out, (unsigned int*)xb, (unsigned int*)wqkvT,
      (unsigned int*)woutT);

  // 1) qkv = x @ w_qkv  (bf16 MFMA, fp32 out)
  gemm_bt_bf16<<<dim3(3 * C_DIM / 128, T_SEQ / 128), blk, 0, stream>>>(
      xb, wqkvT, qkv, T_SEQ, 3 * C_DIM, C_DIM);

  // 2) RoPE + bf16 split (+ V transpose)
  rope_split_bf16<<<dim3(T_SEQ / 64, N_HEADS), blk, 0, stream>>>(qkv, Qb, Kb,
                                                                 Vt);

  // 3) flash attention (hoisted addresses + explicit vmcnt drains)
  attn_mfma<<<dim3(1024), blk, 0, stream>>>(Qb, Kb, Vt, attn_ob);

  // 4) out = attn_o @ w_out (64x64 tiles, 1024 blocks = 4/CU)
  gemm_bt_bf16_64<<<dim3(C_DIM / 64, T_SEQ / 64), blk, 0, stream>>>(
      attn_ob, woutT, out, T_SEQ, C_DIM, C_DIM);
}

// Round 11
// 231.900 us; speedup vs baseline: 1.0001x; 1.0001x over previous
//
#include <hip/hip_runtime.h>
#include <hip/hip_bf16.h>
#include <math.h>

// Problem constants (B=1)
#define T_SEQ 4096
#define C_DIM 1024
#define N_HEADS 16
#define HEAD_D 64

typedef __bf16 bf16x8 __attribute__((ext_vector_type(8)));
typedef float f32x4 __attribute__((ext_vector_type(4)));

__device__ __forceinline__ unsigned int pack_bf16x2(float lo, float hi) {
  unsigned short a = __builtin_bit_cast(unsigned short, __float2bfloat16(lo));
  unsigned short b = __builtin_bit_cast(unsigned short, __float2bfloat16(hi));
  return (unsigned int)a | ((unsigned int)b << 16);
}

// Async global->LDS, 16B per lane, wave-uniform LDS base + lane*16.
__device__ __forceinline__ void load_lds16(const void* g, void* l) {
  __builtin_amdgcn_global_load_lds(
      (const __attribute__((address_space(1))) unsigned int*)g,
      (__attribute__((address_space(3))) unsigned int*)l, 16, 0, 0);
}

// Raw barrier + explicit vm waits (attn K-loop protocol). Each wave's LDS
// reads are complete before it reaches a barrier (MFMA data deps force the
// lgkmcnt waits), so s_barrier needs no implicit full drain.
#define WAITCNT_VM0 asm volatile("s_waitcnt vmcnt(0)" ::: "memory")
#define WAITCNT_VM2 asm volatile("s_waitcnt vmcnt(2)" ::: "memory")
__device__ __forceinline__ void block_barrier() {
  asm volatile("s_barrier" ::: "memory");
}

// ---------------------------------------------------------------------------
// prep: x cast (blocks 0..2047) + w_qkv transpose (2048..2815) + w_out
// transpose (2816..3071). One launch.
// ---------------------------------------------------------------------------
__global__ __launch_bounds__(256) void prep_inputs(
    const float* __restrict__ x, const float* __restrict__ w_qkv,
    const float* __restrict__ w_out, unsigned int* __restrict__ xb,
    unsigned int* __restrict__ wqkvT, unsigned int* __restrict__ woutT) {
  __shared__ float tile[64][65];
  const int b = blockIdx.x;
  const int tid = threadIdx.x;

  if (b < 2048) {  // cast x -> bf16, 8 elems/thread
    const int i = b * 256 + tid;
    const float4 a = ((const float4*)x)[2 * i];
    const float4 c = ((const float4*)x)[2 * i + 1];
    uint4 r;
    r.x = pack_bf16x2(a.x, a.y);
    r.y = pack_bf16x2(a.z, a.w);
    r.z = pack_bf16x2(c.x, c.y);
    r.w = pack_bf16x2(c.z, c.w);
    ((uint4*)xb)[i] = r;
    return;
  }

  const float* W;
  unsigned int* WT;
  int N, bb;
  if (b < 2816) {
    W = w_qkv; WT = wqkvT; N = 3072; bb = b - 2048;
  } else {
    W = w_out; WT = woutT; N = 1024; bb = b - 2816;
  }
  const int K = 1024;
  const int n0 = (bb % (N / 64)) * 64, k0 = (bb / (N / 64)) * 64;
#pragma unroll
  for (int i = 0; i < 16; i++) {
    const int idx = i * 256 + tid;
    const int r = idx >> 6, c = idx & 63;  // r: k, c: n
    tile[r][c] = W[(size_t)(k0 + r) * N + n0 + c];
  }
  __syncthreads();
#pragma unroll
  for (int i = 0; i < 8; i++) {
    const int idx = i * 256 + tid;
    const int rn = idx >> 5, p = idx & 31;  // rn: n-row, p: k-pair
    WT[((size_t)(n0 + rn) * K + k0) / 2 + p] =
        pack_bf16x2(tile[2 * p][rn], tile[2 * p + 1][rn]);
  }
}

// ---------------------------------------------------------------------------
// bf16 MFMA GEMM (m97 structure, R8 form — no explicit drains):
// C[M][N] f32 = A[M][K]bf16 * Bt[N][K]bf16^T. Tile 128x128, 4 waves 2x2.
// ---------------------------------------------------------------------------
__global__ __launch_bounds__(256) void gemm_bt_bf16(
    const unsigned short* __restrict__ A,   // [M][K]
    const unsigned short* __restrict__ Bt,  // [N][K]
    float* __restrict__ C, int M, int N, int K) {
  __shared__ __align__(16) unsigned short As[128 * 32];
  __shared__ __align__(16) unsigned short Bs[128 * 32];
  const int tid = threadIdx.x;
  const int w = tid >> 6, lane = tid & 63;
  const int quad = lane >> 4, l16 = lane & 15;
  const int bm = blockIdx.y * 128, bn = blockIdx.x * 128;
  const int mw = (w & 1) * 64, nw = (w >> 1) * 64;

  f32x4 acc[4][4];
#pragma unroll
  for (int mt = 0; mt < 4; mt++)
#pragma unroll
    for (int nt = 0; nt < 4; nt++) acc[mt][nt] = (f32x4){0.f, 0.f, 0.f, 0.f};

  const int crow = lane >> 2;
  const int cq = lane & 3;
  const unsigned short* Ab = A + (size_t)bm * K;
  const unsigned short* Bb = Bt + (size_t)bn * K;

  for (int k0 = 0; k0 < K; k0 += 32) {
#pragma unroll
    for (int i = 0; i < 2; i++) {
      const int c = w + i * 4;
      const int row = c * 16 + crow;
      load_lds16(Ab + (size_t)row * K + k0 + cq * 8, As + c * 512);
      load_lds16(Bb + (size_t)row * K + k0 + cq * 8, Bs + c * 512);
    }
    __syncthreads();

    bf16x8 af[4], bf[4];
#pragma unroll
    for (int mt = 0; mt < 4; mt++)
      af[mt] = __builtin_bit_cast(
          bf16x8, *(const int4*)(As + (mw + mt * 16 + l16) * 32 + quad * 8));
#pragma unroll
    for (int nt = 0; nt < 4; nt++)
      bf[nt] = __builtin_bit_cast(
          bf16x8, *(const int4*)(Bs + (nw + nt * 16 + l16) * 32 + quad * 8));
#pragma unroll
    for (int mt = 0; mt < 4; mt++)
#pragma unroll
      for (int nt = 0; nt < 4; nt++)
        acc[mt][nt] = __builtin_amdgcn_mfma_f32_16x16x32_bf16(
            af[mt], bf[nt], acc[mt][nt], 0, 0, 0);
    __syncthreads();
  }

#pragma unroll
  for (int mt = 0; mt < 4; mt++)
#pragma unroll
    for (int nt = 0; nt < 4; nt++)
#pragma unroll
      for (int reg = 0; reg < 4; reg++)
        C[(size_t)(bm + mw + mt * 16 + quad * 4 + reg) * N + bn + nw +
          nt * 16 + l16] = acc[mt][nt][reg];
}

// ---------------------------------------------------------------------------
// 64x64-tile GEMM for the out-projection (R8 form): 1024 blocks -> 4/CU.
// ---------------------------------------------------------------------------
__global__ __launch_bounds__(256) void gemm_bt_bf16_64(
    const unsigned short* __restrict__ A,   // [M][K]
    const unsigned short* __restrict__ Bt,  // [N][K]
    float* __restrict__ C, int M, int N, int K) {
  __shared__ __align__(16) unsigned short As[64 * 32];
  __shared__ __align__(16) unsigned short Bs[64 * 32];
  const int tid = threadIdx.x;
  const int w = tid >> 6, lane = tid & 63;
  const int quad = lane >> 4, l16 = lane & 15;
  const int bm = blockIdx.y * 64, bn = blockIdx.x * 64;
  const int mw = (w & 1) * 32, nw = (w >> 1) * 32;

  f32x4 acc[2][2];
#pragma unroll
  for (int mt = 0; mt < 2; mt++)
#pragma unroll
    for (int nt = 0; nt < 2; nt++) acc[mt][nt] = (f32x4){0.f, 0.f, 0.f, 0.f};

  const unsigned short* Ab = A + (size_t)bm * K;
  const unsigned short* Bb = Bt + (size_t)bn * K;
  const int srow = w * 16 + (lane >> 2);
  const int scol = (lane & 3) * 8;

  for (int k0 = 0; k0 < K; k0 += 32) {
    load_lds16(Ab + (size_t)srow * K + k0 + scol, As + w * 512);
    load_lds16(Bb + (size_t)srow * K + k0 + scol, Bs + w * 512);
    __syncthreads();

    bf16x8 af[2], bf[2];
#pragma unroll
    for (int mt = 0; mt < 2; mt++)
      af[mt] = __builtin_bit_cast(
          bf16x8, *(const int4*)(As + (mw + mt * 16 + l16) * 32 + quad * 8));
#pragma unroll
    for (int nt = 0; nt < 2; nt++)
      bf[nt] = __builtin_bit_cast(
          bf16x8, *(const int4*)(Bs + (nw + nt * 16 + l16) * 32 + quad * 8));
#pragma unroll
    for (int mt = 0; mt < 2; mt++)
#pragma unroll
      for (int nt = 0; nt < 2; nt++)
        acc[mt][nt] = __builtin_amdgcn_mfma_f32_16x16x32_bf16(
            af[mt], bf[nt], acc[mt][nt], 0, 0, 0);
    __syncthreads();
  }

#pragma unroll
  for (int mt = 0; mt < 2; mt++)
#pragma unroll
    for (int nt = 0; nt < 2; nt++)
#pragma unroll
      for (int reg = 0; reg < 4; reg++)
        C[(size_t)(bm + mw + mt * 16 + quad * 4 + reg) * N + bn + nw +
          nt * 16 + l16] = acc[mt][nt][reg];
}

// ---------------------------------------------------------------------------
// RoPE + split to bf16: Qb[h][t][d] (PRE-SCALED by 0.125*log2(e)),
// Kb[h][t][d], Vt[h][d][t] (transposed). Reads fp32 qkv.
// ---------------------------------------------------------------------------
__global__ __launch_bounds__(256) void rope_split_bf16(
    const float* __restrict__ qkv, unsigned short* __restrict__ Qb,
    unsigned short* __restrict__ Kb, unsigned short* __restrict__ Vt) {
  const int tb = blockIdx.x * 64;
  const int h = blockIdx.y;
  const int tid = threadIdx.x;

  const int j = tid & 31;
  const int r0 = tid >> 5;  // 0..7
  const float inv = powf(10000.0f, -(2.0f * (float)j) / 64.0f);
  const float QSCALE = 0.125f * 1.44269504089f;  // 1/sqrt(D) * log2(e)
  unsigned int* Qu = (unsigned int*)Qb;
  unsigned int* Ku = (unsigned int*)Kb;
#pragma unroll
  for (int rr = 0; rr < 8; rr++) {
    const int t = tb + r0 + rr * 8;
    float s, c;
    sincosf((float)t * inv, &s, &c);
    const float* base = qkv + (size_t)t * (3 * C_DIM) + h * HEAD_D + 2 * j;
    const float2 q2 = *(const float2*)(base);
    const float2 k2 = *(const float2*)(base + C_DIM);
    const float qe = (q2.x * c - q2.y * s) * QSCALE;
    const float qo = (q2.y * c + q2.x * s) * QSCALE;
    const float ke = k2.x * c - k2.y * s;
    const float ko = k2.y * c + k2.x * s;
    const size_t ridx = ((size_t)h * T_SEQ + t) * 32 + j;
    Qu[ridx] = pack_bf16x2(qe, qo);
    Ku[ridx] = pack_bf16x2(ke, ko);
  }

  __shared__ float vs[64][65];
#pragma unroll
  for (int i = 0; i < 16; i++) {
    const int idx = i * 256 + tid;
    const int r = idx >> 6, d = idx & 63;
    vs[r][d] = qkv[(size_t)(tb + r) * (3 * C_DIM) + 2 * C_DIM + h * HEAD_D + d];
  }
  __syncthreads();
  unsigned int* Vu = (unsigned int*)Vt;
#pragma unroll
  for (int i = 0; i < 8; i++) {
    const int idx = i * 256 + tid;
    const int d = idx >> 5, sp = idx & 31;
    Vu[((size_t)(h * HEAD_D + d)) * (T_SEQ / 2) + (tb >> 1) + sp] =
        pack_bf16x2(vs[2 * sp][d], vs[2 * sp + 1][d]);
  }
}

// ---------------------------------------------------------------------------
// Flash attention v4d: V-FIRST staging order + fine-grained vmcnt.
// After barrier1 each iteration: issue V-cur (2 loads) THEN K-next (2 loads).
// Before barrier2: vmcnt(2) -> waits only V-cur (oldest 2), K-next stays in
// flight across PV + next QK phase (vmcnt(0) only on the last iteration).
// Raw s_barrier (no compiler-forced full drain). Operand-swapped MFMA
// (A=K -> S^T; A=V^T -> O^T), qt balance map, K dbuf + V single buffer,
// lsum via all-ones MFMA, hoisted lane-constant LDS addresses.
// LDS 33792 B -> 4 blocks/CU.
// ---------------------------------------------------------------------------
__global__ __launch_bounds__(256) void attn_mfma(
    const unsigned short* __restrict__ Qb, const unsigned short* __restrict__ Kb,
    const unsigned short* __restrict__ Vt, unsigned short* __restrict__ O) {
  const int b = blockIdx.x;
  const int rep = b >> 8;
  const int jj = b & 255;
  const int h = jj & 15;
  const int u = jj >> 4;
  const int qmap[4] = {u, 63 - u, 16 + u, 47 - u};
  const int qt = qmap[rep];

  const int tid = threadIdx.x;
  const int w = tid >> 6;
  const int lane = tid & 63;
  const int quad = lane >> 4;
  const int l16 = lane & 15;
  const int qb = qt * 64;
  const int qw = qb + w * 16;

  __shared__ __align__(16) unsigned short Ks[2][64 * 64];
  __shared__ __align__(16) unsigned short Vs[64 * 64];
  __shared__ __align__(16) unsigned short plds[4][16][72];  // [wave][q][s]

  const unsigned short* Kh = Kb + (size_t)h * T_SEQ * HEAD_D;
  const unsigned short* Vh = Vt + (size_t)h * HEAD_D * T_SEQ;

  // Q B-frags (persist): B[k=d][n=q]: q = l16, d = quad*8+j (+32 for ks=1)
  bf16x8 bq[2];
  {
    const unsigned short* qrow =
        Qb + ((size_t)h * T_SEQ + qw + l16) * HEAD_D + quad * 8;
#pragma unroll
    for (int ks = 0; ks < 2; ks++)
      bq[ks] = __builtin_bit_cast(bf16x8, *(const int4*)(qrow + ks * 32));
  }

  bf16x8 aones;
#pragma unroll
  for (int i = 0; i < 8; i++) aones[i] = (__bf16)1.0f;

  f32x4 o[4];
#pragma unroll
  for (int dt = 0; dt < 4; dt++) o[dt] = (f32x4){0.f, 0.f, 0.f, 0.f};
  f32x4 lacc = (f32x4){0.f, 0.f, 0.f, 0.f};

  // ---- hoisted lane-constant LDS read bases ----
  const int x7 = l16 & 7;
  const int o0 = (quad ^ x7) * 8;  // elements
  const int o1 = o0 ^ 32;
  const int rbase = l16 * 64;
  const unsigned short* k0a = Ks[0] + rbase + o0;
  const unsigned short* k0b = Ks[0] + rbase + o1;
  const unsigned short* k1a = Ks[1] + rbase + o0;
  const unsigned short* k1b = Ks[1] + rbase + o1;
  const unsigned short* va = Vs + rbase + o0;
  const unsigned short* vb = Vs + rbase + o1;
  unsigned short* pw = &plds[w][l16][quad * 4];        // writes: +nt*16
  const unsigned short* pr = &plds[w][l16][quad * 8];  // reads: +0, +32

  // ---- staging: running global pointers ----
  const int sr = tid >> 3;  // row 0..31 (+32 for second issue)
  const int sc = tid & 7;   // 16B chunk
  const int csoff = (sc ^ (sr & 7)) * 8;
  const unsigned short* kgrun = Kh + (size_t)sr * HEAD_D + csoff;
  const unsigned short* vgrun = Vh + (size_t)sr * T_SEQ + csoff;
  const int ntiles = qb / 64 + 1;

  // stage K tile 0
  load_lds16(kgrun, &Ks[0][w * 512]);
  load_lds16(kgrun + 2048, &Ks[0][(4 + w) * 512]);
  kgrun += 4096;

  for (int it = 0; it < ntiles; it++) {
    const int s0 = it * 64;
    const int cur = it & 1;
    const bool pref = (it + 1 < ntiles);  // block-uniform

    // barrier1: K[cur] staged (vmcnt(0) drains it); all waves' Vs reads of
    // the previous iteration completed before they reached this barrier.
    WAITCNT_VM0;
    block_barrier();

    // V first (consumed at barrier2), then K-next (consumed next iteration)
    load_lds16(vgrun, &Vs[w * 512]);
    load_lds16(vgrun + 32 * T_SEQ, &Vs[(4 + w) * 512]);
    vgrun += 64;
    if (pref) {
      unsigned short* kd = &Ks[cur ^ 1][w * 512];
      load_lds16(kgrun, kd);
      load_lds16(kgrun + 2048, kd + 2048);
      kgrun += 4096;
    }

    const unsigned short* ka = cur ? k1a : k0a;
    const unsigned short* kc = cur ? k1b : k0b;

    // S^T = K Q^T; D-layout: key = nt*16 + quad*4 + reg, q = l16.
    f32x4 sv[4];
#pragma unroll
    for (int nt = 0; nt < 4; nt++) {
      const bf16x8 a0 =
          __builtin_bit_cast(bf16x8, *(const int4*)(ka + nt * 1024));
      const bf16x8 a1 =
          __builtin_bit_cast(bf16x8, *(const int4*)(kc + nt * 1024));
      f32x4 z = (f32x4){0.f, 0.f, 0.f, 0.f};
      z = __builtin_amdgcn_mfma_f32_16x16x32_bf16(a0, bq[0], z, 0, 0, 0);
      sv[nt] = __builtin_amdgcn_mfma_f32_16x16x32_bf16(a1, bq[1], z, 0, 0, 0);
    }

    // causal mask: only the diagonal tile is partial
    if (s0 == qb) {
      const int qg = qw + l16;
#pragma unroll
      for (int nt = 0; nt < 4; nt++)
#pragma unroll
        for (int reg = 0; reg < 4; reg++) {
          const int sg = s0 + nt * 16 + quad * 4 + reg;
          if (sg > qg) sv[nt][reg] = -1e30f;
        }
    }

    // p = 2^s, pack 4 consecutive keys -> b64 LDS write (P^T layout [q][s])
#pragma unroll
    for (int nt = 0; nt < 4; nt++) {
      float p0 = exp2f(sv[nt][0]), p1 = exp2f(sv[nt][1]);
      float p2 = exp2f(sv[nt][2]), p3 = exp2f(sv[nt][3]);
      uint2 pk;
      pk.x = pack_bf16x2(p0, p1);
      pk.y = pack_bf16x2(p2, p3);
      *(uint2*)(pw + nt * 16) = pk;
    }

    // B-frags for PV: B[k=s][n=q]
    bf16x8 bp[2];
    bp[0] = __builtin_bit_cast(bf16x8, *(const int4*)(pr));
    bp[1] = __builtin_bit_cast(bf16x8, *(const int4*)(pr + 32));

    // lsum via MFMA (ones-A): D[m][q] = sum_k P^T[k][q]
    lacc = __builtin_amdgcn_mfma_f32_16x16x32_bf16(aones, bp[0], lacc, 0, 0, 0);
    lacc = __builtin_amdgcn_mfma_f32_16x16x32_bf16(aones, bp[1], lacc, 0, 0, 0);

    // barrier2: wait V-cur only (oldest 2 of 4) — K-next stays in flight.
    if (pref) {
      WAITCNT_VM2;
    } else {
      WAITCNT_VM0;
    }
    block_barrier();

    // O^T += V^T P^T
#pragma unroll
    for (int dt = 0; dt < 4; dt++) {
      const bf16x8 a0 =
          __builtin_bit_cast(bf16x8, *(const int4*)(va + dt * 1024));
      const bf16x8 a1 =
          __builtin_bit_cast(bf16x8, *(const int4*)(vb + dt * 1024));
      o[dt] = __builtin_amdgcn_mfma_f32_16x16x32_bf16(a0, bp[0], o[dt], 0, 0, 0);
      o[dt] = __builtin_amdgcn_mfma_f32_16x16x32_bf16(a1, bp[1], o[dt], 0, 0, 0);
    }
  }

  // epilogue: lacc holds full key-sum for q = l16 (replicated) -> no shuffles
  const float invl = 1.0f / lacc[0];
  const int row = qw + l16;
#pragma unroll
  for (int dt = 0; dt < 4; dt++) {
    uint2 pk;
    pk.x = pack_bf16x2(o[dt][0] * invl, o[dt][1] * invl);
    pk.y = pack_bf16x2(o[dt][2] * invl, o[dt][3] * invl);
    *(uint2*)(O + (size_t)row * C_DIM + h * HEAD_D + dt * 16 + quad * 4) = pk;
  }
}

// ---------------------------------------------------------------------------
// Launch (R8 dataflow: fp32 qkv intermediate, rope does V transpose)
// ---------------------------------------------------------------------------
extern "C" void kernel_launch(void* const* d_in, const int* in_sizes, int n_in,
                              void* d_out, int out_size, void* d_ws,
                              size_t ws_size, hipStream_t stream) {
  const float* x = (const float*)d_in[0];      // [T][C]
  const float* w_qkv = (const float*)d_in[1];  // [C][3C]
  const float* w_out = (const float*)d_in[2];  // [C][C]
  float* out = (float*)d_out;                  // [T][C]

  char* ws = (char*)d_ws;
  // Workspace layout (88 MB peak):
  //   [0, 48MB):  qkv fp32 [T][3C]; reused later as attn_ob bf16 [T][C]
  //   [48,56MB):  Qb bf16 [H][T][D] (pre-scaled by 0.125*log2e)
  //   [56,64MB):  Kb bf16 [H][T][D]
  //   [64,72MB):  Vt bf16 [H][D][T]
  //   [72,80MB):  xb bf16 [T][C]
  //   [80,86MB):  wqkvT bf16 [3C][C]
  //   [86,88MB):  woutT bf16 [C][C]
  float* qkv = (float*)ws;
  unsigned short* Qb = (unsigned short*)(ws + (size_t)48 * 1024 * 1024);
  unsigned short* Kb = (unsigned short*)(ws + (size_t)56 * 1024 * 1024);
  unsigned short* Vt = (unsigned short*)(ws + (size_t)64 * 1024 * 1024);
  unsigned short* xb = (unsigned short*)(ws + (size_t)72 * 1024 * 1024);
  unsigned short* wqkvT = (unsigned short*)(ws + (size_t)80 * 1024 * 1024);
  unsigned short* woutT = (unsigned short*)(ws + (size_t)86 * 1024 * 1024);
  unsigned short* attn_ob = (unsigned short*)ws;  // reuse qkv space

  dim3 blk(256);

  // 0) fused cast + transposes
  prep_inputs<<<dim3(3072), blk, 0, stream>>>(
      x, w_qkv, w_out, (unsigned int*)xb, (unsigned int*)wqkvT,
      (unsigned int*)woutT);

  // 1) qkv = x @ w_qkv  (bf16 MFMA, fp32 out)
  gemm_bt_bf16<<<dim3(3 * C_DIM / 128, T_SEQ / 128), blk, 0, stream>>>(
      xb, wqkvT, qkv, T_SEQ, 3 * C_DIM, C_DIM);

  // 2) RoPE + bf16 split (+ V transpose)
  rope_split_bf16<<<dim3(T_SEQ / 64, N_HEADS), blk, 0, stream>>>(qkv, Qb, Kb,
                                                                 Vt);

  // 3) flash attention (V-first staging + vmcnt(2) pipeline)
  attn_mfma<<<dim3(1024), blk, 0, stream>>>(Qb, Kb, Vt, attn_ob);

  // 4) out = attn_o @ w_out (64x64 tiles, 1024 blocks = 4/CU)
  gemm_bt_bf16_64<<<dim3(C_DIM / 64, T_SEQ / 64), blk, 0, stream>>>(
      attn_ob, woutT, out, T_SEQ, C_DIM, C_DIM);
}

// Round 12
// 230.658 us; speedup vs baseline: 1.0055x; 1.0054x over previous
//
#include <hip/hip_runtime.h>
#include <hip/hip_bf16.h>
#include <math.h>

// Problem constants (B=1)
#define T_SEQ 4096
#define C_DIM 1024
#define N_HEADS 16
#define HEAD_D 64

typedef __bf16 bf16x8 __attribute__((ext_vector_type(8)));
typedef float f32x4 __attribute__((ext_vector_type(4)));

__device__ __forceinline__ unsigned int pack_bf16x2(float lo, float hi) {
  unsigned short a = __builtin_bit_cast(unsigned short, __float2bfloat16(lo));
  unsigned short b = __builtin_bit_cast(unsigned short, __float2bfloat16(hi));
  return (unsigned int)a | ((unsigned int)b << 16);
}

__device__ __forceinline__ unsigned short f2bf(float v) {
  return __builtin_bit_cast(unsigned short, __float2bfloat16(v));
}

// Async global->LDS, 16B per lane, wave-uniform LDS base + lane*16.
__device__ __forceinline__ void load_lds16(const void* g, void* l) {
  __builtin_amdgcn_global_load_lds(
      (const __attribute__((address_space(1))) unsigned int*)g,
      (__attribute__((address_space(3))) unsigned int*)l, 16, 0, 0);
}

// Raw barrier + explicit vm waits (attn K-loop protocol, validated R10/R11).
#define WAITCNT_VM0 asm volatile("s_waitcnt vmcnt(0)" ::: "memory")
#define WAITCNT_VM2 asm volatile("s_waitcnt vmcnt(2)" ::: "memory")
__device__ __forceinline__ void block_barrier() {
  asm volatile("s_barrier" ::: "memory");
}

// ---------------------------------------------------------------------------
// prep: x cast (blocks 0..2047) + w_qkv transpose (2048..2815) + w_out
// transpose (2816..3071). One launch.
// ---------------------------------------------------------------------------
__global__ __launch_bounds__(256) void prep_inputs(
    const float* __restrict__ x, const float* __restrict__ w_qkv,
    const float* __restrict__ w_out, unsigned int* __restrict__ xb,
    unsigned int* __restrict__ wqkvT, unsigned int* __restrict__ woutT) {
  __shared__ float tile[64][65];
  const int b = blockIdx.x;
  const int tid = threadIdx.x;

  if (b < 2048) {  // cast x -> bf16, 8 elems/thread
    const int i = b * 256 + tid;
    const float4 a = ((const float4*)x)[2 * i];
    const float4 c = ((const float4*)x)[2 * i + 1];
    uint4 r;
    r.x = pack_bf16x2(a.x, a.y);
    r.y = pack_bf16x2(a.z, a.w);
    r.z = pack_bf16x2(c.x, c.y);
    r.w = pack_bf16x2(c.z, c.w);
    ((uint4*)xb)[i] = r;
    return;
  }

  const float* W;
  unsigned int* WT;
  int N, bb;
  if (b < 2816) {
    W = w_qkv; WT = wqkvT; N = 3072; bb = b - 2048;
  } else {
    W = w_out; WT = woutT; N = 1024; bb = b - 2816;
  }
  const int K = 1024;
  const int n0 = (bb % (N / 64)) * 64, k0 = (bb / (N / 64)) * 64;
#pragma unroll
  for (int i = 0; i < 16; i++) {
    const int idx = i * 256 + tid;
    const int r = idx >> 6, c = idx & 63;  // r: k, c: n
    tile[r][c] = W[(size_t)(k0 + r) * N + n0 + c];
  }
  __syncthreads();
#pragma unroll
  for (int i = 0; i < 8; i++) {
    const int idx = i * 256 + tid;
    const int rn = idx >> 5, p = idx & 31;  // rn: n-row, p: k-pair
    WT[((size_t)(n0 + rn) * K + k0) / 2 + p] =
        pack_bf16x2(tile[2 * p][rn], tile[2 * p + 1][rn]);
  }
}

// ---------------------------------------------------------------------------
// qkv projection GEMM, 128x128 tiles, fused epilogue (R9 dataflow):
//   cols < 2048 (Q,K): bf16 scalar stores to qkvb [T][3072] (Q,K thirds)
//   cols >= 2048 (V):  packed 4x-bf16 stores DIRECTLY to Vt [h*64+d][t]
//                      (C/D layout regs = 4 consecutive t -> free transpose)
// Standard __syncthreads (full drain) staging protocol — known-good m97 form.
// ---------------------------------------------------------------------------
__global__ __launch_bounds__(256) void gemm_qkv(
    const unsigned short* __restrict__ A,   // xb [4096][1024]
    const unsigned short* __restrict__ Bt,  // wqkvT [3072][1024]
    unsigned short* __restrict__ qkvb,      // bf16 [T][3072] (Q,K thirds used)
    unsigned short* __restrict__ Vt) {      // bf16 [1024][4096]
  const int K = 1024;
  __shared__ __align__(16) unsigned short As[128 * 32];
  __shared__ __align__(16) unsigned short Bs[128 * 32];
  const int tid = threadIdx.x;
  const int w = tid >> 6, lane = tid & 63;
  const int quad = lane >> 4, l16 = lane & 15;
  const int bm = blockIdx.y * 128, bn = blockIdx.x * 128;
  const int mw = (w & 1) * 64, nw = (w >> 1) * 64;

  f32x4 acc[4][4];
#pragma unroll
  for (int mt = 0; mt < 4; mt++)
#pragma unroll
    for (int nt = 0; nt < 4; nt++) acc[mt][nt] = (f32x4){0.f, 0.f, 0.f, 0.f};

  const int crow = lane >> 2;
  const int cq = lane & 3;
  const unsigned short* Ab = A + (size_t)bm * K;
  const unsigned short* Bb = Bt + (size_t)bn * K;

  for (int k0 = 0; k0 < K; k0 += 32) {
#pragma unroll
    for (int i = 0; i < 2; i++) {
      const int c = w + i * 4;
      const int row = c * 16 + crow;
      load_lds16(Ab + (size_t)row * K + k0 + cq * 8, As + c * 512);
      load_lds16(Bb + (size_t)row * K + k0 + cq * 8, Bs + c * 512);
    }
    __syncthreads();

    bf16x8 af[4], bf[4];
#pragma unroll
    for (int mt = 0; mt < 4; mt++)
      af[mt] = __builtin_bit_cast(
          bf16x8, *(const int4*)(As + (mw + mt * 16 + l16) * 32 + quad * 8));
#pragma unroll
    for (int nt = 0; nt < 4; nt++)
      bf[nt] = __builtin_bit_cast(
          bf16x8, *(const int4*)(Bs + (nw + nt * 16 + l16) * 32 + quad * 8));
#pragma unroll
    for (int mt = 0; mt < 4; mt++)
#pragma unroll
      for (int nt = 0; nt < 4; nt++)
        acc[mt][nt] = __builtin_amdgcn_mfma_f32_16x16x32_bf16(
            af[mt], bf[nt], acc[mt][nt], 0, 0, 0);
    __syncthreads();
  }

  if (bn >= 2048) {  // V block: packed stores to Vt[d_global][t]
#pragma unroll
    for (int mt = 0; mt < 4; mt++)
#pragma unroll
      for (int nt = 0; nt < 4; nt++) {
        const int dg = bn + nw + nt * 16 + l16 - 2048;  // 0..1023
        const int t0 = bm + mw + mt * 16 + quad * 4;
        uint2 pk;
        pk.x = pack_bf16x2(acc[mt][nt][0], acc[mt][nt][1]);
        pk.y = pack_bf16x2(acc[mt][nt][2], acc[mt][nt][3]);
        *(uint2*)(Vt + (size_t)dg * T_SEQ + t0) = pk;
      }
  } else {  // Q/K block: bf16 scalar stores to qkvb
#pragma unroll
    for (int mt = 0; mt < 4; mt++)
#pragma unroll
      for (int nt = 0; nt < 4; nt++)
#pragma unroll
        for (int reg = 0; reg < 4; reg++)
          qkvb[(size_t)(bm + mw + mt * 16 + quad * 4 + reg) * 3072 + bn + nw +
               nt * 16 + l16] = f2bf(acc[mt][nt][reg]);
  }
}

// ---------------------------------------------------------------------------
// 64x64-tile GEMM for the out-projection: 1024 blocks -> 4/CU. fp32 out.
// ---------------------------------------------------------------------------
__global__ __launch_bounds__(256) void gemm_bt_bf16_64(
    const unsigned short* __restrict__ A,   // [M][K]
    const unsigned short* __restrict__ Bt,  // [N][K]
    float* __restrict__ C, int M, int N, int K) {
  __shared__ __align__(16) unsigned short As[64 * 32];
  __shared__ __align__(16) unsigned short Bs[64 * 32];
  const int tid = threadIdx.x;
  const int w = tid >> 6, lane = tid & 63;
  const int quad = lane >> 4, l16 = lane & 15;
  const int bm = blockIdx.y * 64, bn = blockIdx.x * 64;
  const int mw = (w & 1) * 32, nw = (w >> 1) * 32;

  f32x4 acc[2][2];
#pragma unroll
  for (int mt = 0; mt < 2; mt++)
#pragma unroll
    for (int nt = 0; nt < 2; nt++) acc[mt][nt] = (f32x4){0.f, 0.f, 0.f, 0.f};

  const unsigned short* Ab = A + (size_t)bm * K;
  const unsigned short* Bb = Bt + (size_t)bn * K;
  const int srow = w * 16 + (lane >> 2);
  const int scol = (lane & 3) * 8;

  for (int k0 = 0; k0 < K; k0 += 32) {
    load_lds16(Ab + (size_t)srow * K + k0 + scol, As + w * 512);
    load_lds16(Bb + (size_t)srow * K + k0 + scol, Bs + w * 512);
    __syncthreads();

    bf16x8 af[2], bf[2];
#pragma unroll
    for (int mt = 0; mt < 2; mt++)
      af[mt] = __builtin_bit_cast(
          bf16x8, *(const int4*)(As + (mw + mt * 16 + l16) * 32 + quad * 8));
#pragma unroll
    for (int nt = 0; nt < 2; nt++)
      bf[nt] = __builtin_bit_cast(
          bf16x8, *(const int4*)(Bs + (nw + nt * 16 + l16) * 32 + quad * 8));
#pragma unroll
    for (int mt = 0; mt < 2; mt++)
#pragma unroll
      for (int nt = 0; nt < 2; nt++)
        acc[mt][nt] = __builtin_amdgcn_mfma_f32_16x16x32_bf16(
            af[mt], bf[nt], acc[mt][nt], 0, 0, 0);
    __syncthreads();
  }

#pragma unroll
  for (int mt = 0; mt < 2; mt++)
#pragma unroll
    for (int nt = 0; nt < 2; nt++)
#pragma unroll
      for (int reg = 0; reg < 4; reg++)
        C[(size_t)(bm + mw + mt * 16 + quad * 4 + reg) * N + bn + nw +
          nt * 16 + l16] = acc[mt][nt][reg];
}

// ---------------------------------------------------------------------------
// RoPE on bf16 qkvb (Q pre-scaled by 0.125*log2e) -> Qb/Kb [h][t][d].
// V untouched (gemm_qkv wrote Vt directly).
// ---------------------------------------------------------------------------
__global__ __launch_bounds__(256) void rope_qk_bf16(
    const unsigned int* __restrict__ qkvb_u,  // bf16-pair view [T][1536]
    unsigned int* __restrict__ Qu, unsigned int* __restrict__ Ku) {
  const int tb = blockIdx.x * 64;
  const int h = blockIdx.y;
  const int tid = threadIdx.x;

  const int j = tid & 31;
  const int r0 = tid >> 5;  // 0..7
  const float inv = powf(10000.0f, -(2.0f * (float)j) / 64.0f);
  const float QSCALE = 0.125f * 1.44269504089f;  // 1/sqrt(D) * log2(e)
#pragma unroll
  for (int rr = 0; rr < 8; rr++) {
    const int t = tb + r0 + rr * 8;
    float s, c;
    sincosf((float)t * inv, &s, &c);
    const unsigned int* src = qkvb_u + (size_t)t * 1536 + h * 32 + j;
    const unsigned int qu = src[0];
    const unsigned int ku = src[512];  // +1024 ushorts
    const float qx = __uint_as_float(qu << 16);
    const float qy = __uint_as_float(qu & 0xffff0000u);
    const float kx = __uint_as_float(ku << 16);
    const float ky = __uint_as_float(ku & 0xffff0000u);
    const float qe = (qx * c - qy * s) * QSCALE;
    const float qo = (qy * c + qx * s) * QSCALE;
    const float ke = kx * c - ky * s;
    const float ko = ky * c + kx * s;
    const size_t ridx = ((size_t)h * T_SEQ + t) * 32 + j;
    Qu[ridx] = pack_bf16x2(qe, qo);
    Ku[ridx] = pack_bf16x2(ke, ko);
  }
}

// ---------------------------------------------------------------------------
// Flash attention v4d (VERBATIM from R11, replay-validated): V-first staging
// + fine-grained vmcnt, raw s_barrier, operand-swapped MFMA, qt balance map,
// K dbuf + V single buffer, lsum via all-ones MFMA, hoisted LDS addresses.
// LDS 33792 B -> 4 blocks/CU.
// ---------------------------------------------------------------------------
__global__ __launch_bounds__(256) void attn_mfma(
    const unsigned short* __restrict__ Qb, const unsigned short* __restrict__ Kb,
    const unsigned short* __restrict__ Vt, unsigned short* __restrict__ O) {
  const int b = blockIdx.x;
  const int rep = b >> 8;
  const int jj = b & 255;
  const int h = jj & 15;
  const int u = jj >> 4;
  const int qmap[4] = {u, 63 - u, 16 + u, 47 - u};
  const int qt = qmap[rep];

  const int tid = threadIdx.x;
  const int w = tid >> 6;
  const int lane = tid & 63;
  const int quad = lane >> 4;
  const int l16 = lane & 15;
  const int qb = qt * 64;
  const int qw = qb + w * 16;

  __shared__ __align__(16) unsigned short Ks[2][64 * 64];
  __shared__ __align__(16) unsigned short Vs[64 * 64];
  __shared__ __align__(16) unsigned short plds[4][16][72];  // [wave][q][s]

  const unsigned short* Kh = Kb + (size_t)h * T_SEQ * HEAD_D;
  const unsigned short* Vh = Vt + (size_t)h * HEAD_D * T_SEQ;

  // Q B-frags (persist): B[k=d][n=q]: q = l16, d = quad*8+j (+32 for ks=1)
  bf16x8 bq[2];
  {
    const unsigned short* qrow =
        Qb + ((size_t)h * T_SEQ + qw + l16) * HEAD_D + quad * 8;
#pragma unroll
    for (int ks = 0; ks < 2; ks++)
      bq[ks] = __builtin_bit_cast(bf16x8, *(const int4*)(qrow + ks * 32));
  }

  bf16x8 aones;
#pragma unroll
  for (int i = 0; i < 8; i++) aones[i] = (__bf16)1.0f;

  f32x4 o[4];
#pragma unroll
  for (int dt = 0; dt < 4; dt++) o[dt] = (f32x4){0.f, 0.f, 0.f, 0.f};
  f32x4 lacc = (f32x4){0.f, 0.f, 0.f, 0.f};

  // ---- hoisted lane-constant LDS read bases ----
  const int x7 = l16 & 7;
  const int o0 = (quad ^ x7) * 8;  // elements
  const int o1 = o0 ^ 32;
  const int rbase = l16 * 64;
  const unsigned short* k0a = Ks[0] + rbase + o0;
  const unsigned short* k0b = Ks[0] + rbase + o1;
  const unsigned short* k1a = Ks[1] + rbase + o0;
  const unsigned short* k1b = Ks[1] + rbase + o1;
  const unsigned short* va = Vs + rbase + o0;
  const unsigned short* vb = Vs + rbase + o1;
  unsigned short* pw = &plds[w][l16][quad * 4];        // writes: +nt*16
  const unsigned short* pr = &plds[w][l16][quad * 8];  // reads: +0, +32

  // ---- staging: running global pointers ----
  const int sr = tid >> 3;  // row 0..31 (+32 for second issue)
  const int sc = tid & 7;   // 16B chunk
  const int csoff = (sc ^ (sr & 7)) * 8;
  const unsigned short* kgrun = Kh + (size_t)sr * HEAD_D + csoff;
  const unsigned short* vgrun = Vh + (size_t)sr * T_SEQ + csoff;
  const int ntiles = qb / 64 + 1;

  // stage K tile 0
  load_lds16(kgrun, &Ks[0][w * 512]);
  load_lds16(kgrun + 2048, &Ks[0][(4 + w) * 512]);
  kgrun += 4096;

  for (int it = 0; it < ntiles; it++) {
    const int s0 = it * 64;
    const int cur = it & 1;
    const bool pref = (it + 1 < ntiles);  // block-uniform

    // barrier1: K[cur] staged (vmcnt(0) drains it); all waves' Vs reads of
    // the previous iteration completed before they reached this barrier.
    WAITCNT_VM0;
    block_barrier();

    // V first (consumed at barrier2), then K-next (consumed next iteration)
    load_lds16(vgrun, &Vs[w * 512]);
    load_lds16(vgrun + 32 * T_SEQ, &Vs[(4 + w) * 512]);
    vgrun += 64;
    if (pref) {
      unsigned short* kd = &Ks[cur ^ 1][w * 512];
      load_lds16(kgrun, kd);
      load_lds16(kgrun + 2048, kd + 2048);
      kgrun += 4096;
    }

    const unsigned short* ka = cur ? k1a : k0a;
    const unsigned short* kc = cur ? k1b : k0b;

    // S^T = K Q^T; D-layout: key = nt*16 + quad*4 + reg, q = l16.
    f32x4 sv[4];
#pragma unroll
    for (int nt = 0; nt < 4; nt++) {
      const bf16x8 a0 =
          __builtin_bit_cast(bf16x8, *(const int4*)(ka + nt * 1024));
      const bf16x8 a1 =
          __builtin_bit_cast(bf16x8, *(const int4*)(kc + nt * 1024));
      f32x4 z = (f32x4){0.f, 0.f, 0.f, 0.f};
      z = __builtin_amdgcn_mfma_f32_16x16x32_bf16(a0, bq[0], z, 0, 0, 0);
      sv[nt] = __builtin_amdgcn_mfma_f32_16x16x32_bf16(a1, bq[1], z, 0, 0, 0);
    }

    // causal mask: only the diagonal tile is partial
    if (s0 == qb) {
      const int qg = qw + l16;
#pragma unroll
      for (int nt = 0; nt < 4; nt++)
#pragma unroll
        for (int reg = 0; reg < 4; reg++) {
          const int sg = s0 + nt * 16 + quad * 4 + reg;
          if (sg > qg) sv[nt][reg] = -1e30f;
        }
    }

    // p = 2^s, pack 4 consecutive keys -> b64 LDS write (P^T layout [q][s])
#pragma unroll
    for (int nt = 0; nt < 4; nt++) {
      float p0 = exp2f(sv[nt][0]), p1 = exp2f(sv[nt][1]);
      float p2 = exp2f(sv[nt][2]), p3 = exp2f(sv[nt][3]);
      uint2 pk;
      pk.x = pack_bf16x2(p0, p1);
      pk.y = pack_bf16x2(p2, p3);
      *(uint2*)(pw + nt * 16) = pk;
    }

    // B-frags for PV: B[k=s][n=q]
    bf16x8 bp[2];
    bp[0] = __builtin_bit_cast(bf16x8, *(const int4*)(pr));
    bp[1] = __builtin_bit_cast(bf16x8, *(const int4*)(pr + 32));

    // lsum via MFMA (ones-A): D[m][q] = sum_k P^T[k][q]
    lacc = __builtin_amdgcn_mfma_f32_16x16x32_bf16(aones, bp[0], lacc, 0, 0, 0);
    lacc = __builtin_amdgcn_mfma_f32_16x16x32_bf16(aones, bp[1], lacc, 0, 0, 0);

    // barrier2: wait V-cur only (oldest 2 of 4) — K-next stays in flight.
    if (pref) {
      WAITCNT_VM2;
    } else {
      WAITCNT_VM0;
    }
    block_barrier();

    // O^T += V^T P^T
#pragma unroll
    for (int dt = 0; dt < 4; dt++) {
      const bf16x8 a0 =
          __builtin_bit_cast(bf16x8, *(const int4*)(va + dt * 1024));
      const bf16x8 a1 =
          __builtin_bit_cast(bf16x8, *(const int4*)(vb + dt * 1024));
      o[dt] = __builtin_amdgcn_mfma_f32_16x16x32_bf16(a0, bp[0], o[dt], 0, 0, 0);
      o[dt] = __builtin_amdgcn_mfma_f32_16x16x32_bf16(a1, bp[1], o[dt], 0, 0, 0);
    }
  }

  // epilogue: lacc holds full key-sum for q = l16 (replicated) -> no shuffles
  const float invl = 1.0f / lacc[0];
  const int row = qw + l16;
#pragma unroll
  for (int dt = 0; dt < 4; dt++) {
    uint2 pk;
    pk.x = pack_bf16x2(o[dt][0] * invl, o[dt][1] * invl);
    pk.y = pack_bf16x2(o[dt][2] * invl, o[dt][3] * invl);
    *(uint2*)(O + (size_t)row * C_DIM + h * HEAD_D + dt * 16 + quad * 4) = pk;
  }
}

// ---------------------------------------------------------------------------
// Launch (R9 dataflow: bf16 qkvb, V written directly to Vt by gemm_qkv)
// ---------------------------------------------------------------------------
extern "C" void kernel_launch(void* const* d_in, const int* in_sizes, int n_in,
                              void* d_out, int out_size, void* d_ws,
                              size_t ws_size, hipStream_t stream) {
  const float* x = (const float*)d_in[0];      // [T][C]
  const float* w_qkv = (const float*)d_in[1];  // [C][3C]
  const float* w_out = (const float*)d_in[2];  // [C][C]
  float* out = (float*)d_out;                  // [T][C]

  char* ws = (char*)d_ws;
  // Workspace layout (88 MB peak):
  //   [0, 24MB):  qkvb bf16 [T][3072] (Q,K thirds); later attn_ob bf16 [T][C]
  //   [48,56MB):  Qb bf16 [H][T][D] (pre-scaled by 0.125*log2e)
  //   [56,64MB):  Kb bf16 [H][T][D]
  //   [64,72MB):  Vt bf16 [H][D][T] (written by gemm_qkv epilogue)
  //   [72,80MB):  xb bf16 [T][C]
  //   [80,86MB):  wqkvT bf16 [3C][C]
  //   [86,88MB):  woutT bf16 [C][C]
  unsigned short* qkvb = (unsigned short*)ws;
  unsigned short* Qb = (unsigned short*)(ws + (size_t)48 * 1024 * 1024);
  unsigned short* Kb = (unsigned short*)(ws + (size_t)56 * 1024 * 1024);
  unsigned short* Vt = (unsigned short*)(ws + (size_t)64 * 1024 * 1024);
  unsigned short* xb = (unsigned short*)(ws + (size_t)72 * 1024 * 1024);
  unsigned short* wqkvT = (unsigned short*)(ws + (size_t)80 * 1024 * 1024);
  unsigned short* woutT = (unsigned short*)(ws + (size_t)86 * 1024 * 1024);
  unsigned short* attn_ob = (unsigned short*)ws;  // reuse qkvb space

  dim3 blk(256);

  // 0) fused cast + transposes
  prep_inputs<<<dim3(3072), blk, 0, stream>>>(
      x, w_qkv, w_out, (unsigned int*)xb, (unsigned int*)wqkvT,
      (unsigned int*)woutT);

  // 1) qkv projection; Q/K -> qkvb bf16, V -> Vt directly
  gemm_qkv<<<dim3(3072 / 128, T_SEQ / 128), blk, 0, stream>>>(xb, wqkvT, qkvb,
                                                              Vt);

  // 2) RoPE on Q/K only (bf16 in/out)
  rope_qk_bf16<<<dim3(T_SEQ / 64, N_HEADS), blk, 0, stream>>>(
      (const unsigned int*)qkvb, (unsigned int*)Qb, (unsigned int*)Kb);

  // 3) flash attention (R11 replay-validated protocol)
  attn_mfma<<<dim3(1024), blk, 0, stream>>>(Qb, Kb, Vt, attn_ob);

  // 4) out = attn_o @ w_out (64x64 tiles, 1024 blocks = 4/CU)
  gemm_bt_bf16_64<<<dim3(C_DIM / 64, T_SEQ / 64), blk, 0, stream>>>(
      attn_ob, woutT, out, T_SEQ, C_DIM, C_DIM);
}

// Round 13
// 222.237 us; speedup vs baseline: 1.0436x; 1.0379x over previous
//
#include <hip/hip_runtime.h>
#include <hip/hip_bf16.h>
#include <math.h>

// Problem constants (B=1)
#define T_SEQ 4096
#define C_DIM 1024
#define N_HEADS 16
#define HEAD_D 64

typedef __bf16 bf16x8 __attribute__((ext_vector_type(8)));
typedef float f32x4 __attribute__((ext_vector_type(4)));

__device__ __forceinline__ unsigned int pack_bf16x2(float lo, float hi) {
  unsigned short a = __builtin_bit_cast(unsigned short, __float2bfloat16(lo));
  unsigned short b = __builtin_bit_cast(unsigned short, __float2bfloat16(hi));
  return (unsigned int)a | ((unsigned int)b << 16);
}

__device__ __forceinline__ unsigned short f2bf(float v) {
  return __builtin_bit_cast(unsigned short, __float2bfloat16(v));
}

// Async global->LDS, 16B per lane, wave-uniform LDS base + lane*16.
__device__ __forceinline__ void load_lds16(const void* g, void* l) {
  __builtin_amdgcn_global_load_lds(
      (const __attribute__((address_space(1))) unsigned int*)g,
      (__attribute__((address_space(3))) unsigned int*)l, 16, 0, 0);
}

// Raw barrier + explicit vm waits (attn K-loop protocol, validated R10-R12).
#define WAITCNT_VM0 asm volatile("s_waitcnt vmcnt(0)" ::: "memory")
#define WAITCNT_VM2 asm volatile("s_waitcnt vmcnt(2)" ::: "memory")
__device__ __forceinline__ void block_barrier() {
  asm volatile("s_barrier" ::: "memory");
}

// ---------------------------------------------------------------------------
// prep: x cast (blocks 0..2047) + w_qkv transpose (2048..2815) + w_out
// transpose (2816..3071) + RoPE cos/sin table (3072..3103). One launch.
// ---------------------------------------------------------------------------
__global__ __launch_bounds__(256) void prep_inputs(
    const float* __restrict__ x, const float* __restrict__ w_qkv,
    const float* __restrict__ w_out, unsigned int* __restrict__ xb,
    unsigned int* __restrict__ wqkvT, unsigned int* __restrict__ woutT,
    float2* __restrict__ cs) {
  __shared__ float tile[64][65];
  const int b = blockIdx.x;
  const int tid = threadIdx.x;

  if (b < 2048) {  // cast x -> bf16, 8 elems/thread
    const int i = b * 256 + tid;
    const float4 a = ((const float4*)x)[2 * i];
    const float4 c = ((const float4*)x)[2 * i + 1];
    uint4 r;
    r.x = pack_bf16x2(a.x, a.y);
    r.y = pack_bf16x2(a.z, a.w);
    r.z = pack_bf16x2(c.x, c.y);
    r.w = pack_bf16x2(c.z, c.w);
    ((uint4*)xb)[i] = r;
    return;
  }

  if (b >= 3072) {  // cos/sin table: cs[t*32+j] = (cos, sin)(t * theta^-2j/64)
    const int bb2 = b - 3072;  // 0..31
#pragma unroll
    for (int i = 0; i < 16; i++) {
      const int idx = bb2 * 4096 + i * 256 + tid;  // 0..131071
      const int t = idx >> 5, j = idx & 31;
      const float inv = powf(10000.0f, -(2.0f * (float)j) / 64.0f);
      float s, c;
      sincosf((float)t * inv, &s, &c);
      cs[idx] = make_float2(c, s);
    }
    return;
  }

  const float* W;
  unsigned int* WT;
  int N, bb;
  if (b < 2816) {
    W = w_qkv; WT = wqkvT; N = 3072; bb = b - 2048;
  } else {
    W = w_out; WT = woutT; N = 1024; bb = b - 2816;
  }
  const int K = 1024;
  const int n0 = (bb % (N / 64)) * 64, k0 = (bb / (N / 64)) * 64;
#pragma unroll
  for (int i = 0; i < 16; i++) {
    const int idx = i * 256 + tid;
    const int r = idx >> 6, c = idx & 63;  // r: k, c: n
    tile[r][c] = W[(size_t)(k0 + r) * N + n0 + c];
  }
  __syncthreads();
#pragma unroll
  for (int i = 0; i < 8; i++) {
    const int idx = i * 256 + tid;
    const int rn = idx >> 5, p = idx & 31;  // rn: n-row, p: k-pair
    WT[((size_t)(n0 + rn) * K + k0) / 2 + p] =
        pack_bf16x2(tile[2 * p][rn], tile[2 * p + 1][rn]);
  }
}

// ---------------------------------------------------------------------------
// qkv projection GEMM, 128x128 tiles, FULLY fused epilogue:
//   Q cols (<1024):      RoPE (fp32, via shfl_xor(1) pair + cs table),
//                        pre-scale 0.125*log2e, bf16 -> Qb[h][t][d]
//   K cols (1024..2047): RoPE, bf16 -> Kb[h][t][d]
//   V cols (>=2048):     packed 4x-bf16 -> Vt[d][t] (free transpose)
// The rope kernel and qkvb intermediate are eliminated.
// ---------------------------------------------------------------------------
__global__ __launch_bounds__(256) void gemm_qkv_rope(
    const unsigned short* __restrict__ A,   // xb [4096][1024]
    const unsigned short* __restrict__ Bt,  // wqkvT [3072][1024]
    const float2* __restrict__ cs,          // [T][32] (cos, sin)
    unsigned short* __restrict__ Qb,        // bf16 [H][T][64]
    unsigned short* __restrict__ Kb,        // bf16 [H][T][64]
    unsigned short* __restrict__ Vt) {      // bf16 [1024][4096]
  const int K = 1024;
  __shared__ __align__(16) unsigned short As[128 * 32];
  __shared__ __align__(16) unsigned short Bs[128 * 32];
  const int tid = threadIdx.x;
  const int w = tid >> 6, lane = tid & 63;
  const int quad = lane >> 4, l16 = lane & 15;
  const int bm = blockIdx.y * 128, bn = blockIdx.x * 128;
  const int mw = (w & 1) * 64, nw = (w >> 1) * 64;

  f32x4 acc[4][4];
#pragma unroll
  for (int mt = 0; mt < 4; mt++)
#pragma unroll
    for (int nt = 0; nt < 4; nt++) acc[mt][nt] = (f32x4){0.f, 0.f, 0.f, 0.f};

  const int crow = lane >> 2;
  const int cq = lane & 3;
  const unsigned short* Ab = A + (size_t)bm * K;
  const unsigned short* Bb = Bt + (size_t)bn * K;

  for (int k0 = 0; k0 < K; k0 += 32) {
#pragma unroll
    for (int i = 0; i < 2; i++) {
      const int c = w + i * 4;
      const int row = c * 16 + crow;
      load_lds16(Ab + (size_t)row * K + k0 + cq * 8, As + c * 512);
      load_lds16(Bb + (size_t)row * K + k0 + cq * 8, Bs + c * 512);
    }
    __syncthreads();

    bf16x8 af[4], bf[4];
#pragma unroll
    for (int mt = 0; mt < 4; mt++)
      af[mt] = __builtin_bit_cast(
          bf16x8, *(const int4*)(As + (mw + mt * 16 + l16) * 32 + quad * 8));
#pragma unroll
    for (int nt = 0; nt < 4; nt++)
      bf[nt] = __builtin_bit_cast(
          bf16x8, *(const int4*)(Bs + (nw + nt * 16 + l16) * 32 + quad * 8));
#pragma unroll
    for (int mt = 0; mt < 4; mt++)
#pragma unroll
      for (int nt = 0; nt < 4; nt++)
        acc[mt][nt] = __builtin_amdgcn_mfma_f32_16x16x32_bf16(
            af[mt], bf[nt], acc[mt][nt], 0, 0, 0);
    __syncthreads();
  }

  if (bn >= 2048) {  // V block: packed stores to Vt[d_global][t]
#pragma unroll
    for (int mt = 0; mt < 4; mt++)
#pragma unroll
      for (int nt = 0; nt < 4; nt++) {
        const int dg = bn + nw + nt * 16 + l16 - 2048;  // 0..1023
        const int t0 = bm + mw + mt * 16 + quad * 4;
        uint2 pk;
        pk.x = pack_bf16x2(acc[mt][nt][0], acc[mt][nt][1]);
        pk.y = pack_bf16x2(acc[mt][nt][2], acc[mt][nt][3]);
        *(uint2*)(Vt + (size_t)dg * T_SEQ + t0) = pk;
      }
  } else {  // Q/K block: RoPE in fp32, store bf16 to Qb/Kb[h][t][d]
    const bool isQ = (bn < 1024);
    const float qs = isQ ? 0.125f * 1.44269504089f : 1.0f;
    unsigned short* dst = isQ ? Qb : Kb;
    const int fbase = bn - (isQ ? 0 : 1024);
#pragma unroll
    for (int mt = 0; mt < 4; mt++)
#pragma unroll
      for (int nt = 0; nt < 4; nt++) {
        const int f = fbase + nw + nt * 16 + l16;  // 0..1023
        const int h = f >> 6, d = f & 63;
        const int j = d >> 1;
        const float sgn = (d & 1) ? 1.0f : -1.0f;
#pragma unroll
        for (int reg = 0; reg < 4; reg++) {
          const int t = bm + mw + mt * 16 + quad * 4 + reg;
          const float2 cv = cs[t * 32 + j];
          const float own = acc[mt][nt][reg];
          // pair partner (feature d^1) lives in lane^1 (same quad, same t)
          const float part = __shfl_xor(own, 1, 64);
          const float r = (own * cv.x + sgn * part * cv.y) * qs;
          dst[((size_t)h * T_SEQ + t) * HEAD_D + d] = f2bf(r);
        }
      }
  }
}

// ---------------------------------------------------------------------------
// 64x64-tile GEMM, BK=64 (16 k-iters, 8 MFMA/wave/barrier vs 4 at BK=32),
// XOR-chunk-swizzled LDS (row stride 128B would otherwise fully wrap the 32
// banks). grid 1024 -> 4 blocks/CU. fp32 out. For the out-projection.
// ---------------------------------------------------------------------------
__global__ __launch_bounds__(256) void gemm_bt_bf16_64(
    const unsigned short* __restrict__ A,   // [M][K]
    const unsigned short* __restrict__ Bt,  // [N][K]
    float* __restrict__ C, int M, int N, int K) {
  __shared__ __align__(16) unsigned short As[64 * 64];
  __shared__ __align__(16) unsigned short Bs[64 * 64];
  const int tid = threadIdx.x;
  const int w = tid >> 6, lane = tid & 63;
  const int quad = lane >> 4, l16 = lane & 15;
  const int bm = blockIdx.y * 64, bn = blockIdx.x * 64;
  const int mw = (w & 1) * 32, nw = (w >> 1) * 32;

  f32x4 acc[2][2];
#pragma unroll
  for (int mt = 0; mt < 2; mt++)
#pragma unroll
    for (int nt = 0; nt < 2; nt++) acc[mt][nt] = (f32x4){0.f, 0.f, 0.f, 0.f};

  const unsigned short* Ab = A + (size_t)bm * K;
  const unsigned short* Bb = Bt + (size_t)bn * K;

  // staging: chunk slot s = i*256 + tid; row r = s>>3, chunk c8 = s&7;
  // source chunk swizzled: (c8 ^ (r&7)) -> LDS linear s*16B.
  const int sr0 = tid >> 3;       // row for issue 0 (0..31)
  const int sc8 = tid & 7;        // chunk-in-row
  // hoisted fragment read offsets (same algebra as attn, proven):
  const int x7 = l16 & 7;
  const int o0 = (quad ^ x7) * 8;  // k-slice 0 chunk
  const int o1 = o0 ^ 32;          // k-slice 1 chunk (4+quad)^x7

  for (int k0 = 0; k0 < K; k0 += 64) {
#pragma unroll
    for (int i = 0; i < 2; i++) {
      const int r = sr0 + i * 32;
      const int csoff = ((sc8 ^ (r & 7)) * 8);
      load_lds16(Ab + (size_t)r * K + k0 + csoff, As + (i * 256 + (tid & ~63)) * 8);
      load_lds16(Bb + (size_t)r * K + k0 + csoff, Bs + (i * 256 + (tid & ~63)) * 8);
    }
    __syncthreads();

    bf16x8 af[2][2], bf[2][2];
#pragma unroll
    for (int mt = 0; mt < 2; mt++) {
      const unsigned short* ar = As + (mw + mt * 16 + l16) * 64;
      af[mt][0] = __builtin_bit_cast(bf16x8, *(const int4*)(ar + o0));
      af[mt][1] = __builtin_bit_cast(bf16x8, *(const int4*)(ar + o1));
    }
#pragma unroll
    for (int nt = 0; nt < 2; nt++) {
      const unsigned short* br = Bs + (nw + nt * 16 + l16) * 64;
      bf[nt][0] = __builtin_bit_cast(bf16x8, *(const int4*)(br + o0));
      bf[nt][1] = __builtin_bit_cast(bf16x8, *(const int4*)(br + o1));
    }
#pragma unroll
    for (int mt = 0; mt < 2; mt++)
#pragma unroll
      for (int nt = 0; nt < 2; nt++) {
        acc[mt][nt] = __builtin_amdgcn_mfma_f32_16x16x32_bf16(
            af[mt][0], bf[nt][0], acc[mt][nt], 0, 0, 0);
        acc[mt][nt] = __builtin_amdgcn_mfma_f32_16x16x32_bf16(
            af[mt][1], bf[nt][1], acc[mt][nt], 0, 0, 0);
      }
    __syncthreads();
  }

#pragma unroll
  for (int mt = 0; mt < 2; mt++)
#pragma unroll
    for (int nt = 0; nt < 2; nt++)
#pragma unroll
      for (int reg = 0; reg < 4; reg++)
        C[(size_t)(bm + mw + mt * 16 + quad * 4 + reg) * N + bn + nw +
          nt * 16 + l16] = acc[mt][nt][reg];
}

// ---------------------------------------------------------------------------
// Flash attention v4d (VERBATIM, replay-validated R10-R12): V-first staging
// + fine-grained vmcnt, raw s_barrier, operand-swapped MFMA, qt balance map,
// K dbuf + V single buffer, lsum via all-ones MFMA, hoisted LDS addresses.
// LDS 33792 B -> 4 blocks/CU.
// ---------------------------------------------------------------------------
__global__ __launch_bounds__(256) void attn_mfma(
    const unsigned short* __restrict__ Qb, const unsigned short* __restrict__ Kb,
    const unsigned short* __restrict__ Vt, unsigned short* __restrict__ O) {
  const int b = blockIdx.x;
  const int rep = b >> 8;
  const int jj = b & 255;
  const int h = jj & 15;
  const int u = jj >> 4;
  const int qmap[4] = {u, 63 - u, 16 + u, 47 - u};
  const int qt = qmap[rep];

  const int tid = threadIdx.x;
  const int w = tid >> 6;
  const int lane = tid & 63;
  const int quad = lane >> 4;
  const int l16 = lane & 15;
  const int qb = qt * 64;
  const int qw = qb + w * 16;

  __shared__ __align__(16) unsigned short Ks[2][64 * 64];
  __shared__ __align__(16) unsigned short Vs[64 * 64];
  __shared__ __align__(16) unsigned short plds[4][16][72];  // [wave][q][s]

  const unsigned short* Kh = Kb + (size_t)h * T_SEQ * HEAD_D;
  const unsigned short* Vh = Vt + (size_t)h * HEAD_D * T_SEQ;

  // Q B-frags (persist): B[k=d][n=q]: q = l16, d = quad*8+j (+32 for ks=1)
  bf16x8 bq[2];
  {
    const unsigned short* qrow =
        Qb + ((size_t)h * T_SEQ + qw + l16) * HEAD_D + quad * 8;
#pragma unroll
    for (int ks = 0; ks < 2; ks++)
      bq[ks] = __builtin_bit_cast(bf16x8, *(const int4*)(qrow + ks * 32));
  }

  bf16x8 aones;
#pragma unroll
  for (int i = 0; i < 8; i++) aones[i] = (__bf16)1.0f;

  f32x4 o[4];
#pragma unroll
  for (int dt = 0; dt < 4; dt++) o[dt] = (f32x4){0.f, 0.f, 0.f, 0.f};
  f32x4 lacc = (f32x4){0.f, 0.f, 0.f, 0.f};

  // ---- hoisted lane-constant LDS read bases ----
  const int x7 = l16 & 7;
  const int o0 = (quad ^ x7) * 8;  // elements
  const int o1 = o0 ^ 32;
  const int rbase = l16 * 64;
  const unsigned short* k0a = Ks[0] + rbase + o0;
  const unsigned short* k0b = Ks[0] + rbase + o1;
  const unsigned short* k1a = Ks[1] + rbase + o0;
  const unsigned short* k1b = Ks[1] + rbase + o1;
  const unsigned short* va = Vs + rbase + o0;
  const unsigned short* vb = Vs + rbase + o1;
  unsigned short* pw = &plds[w][l16][quad * 4];        // writes: +nt*16
  const unsigned short* pr = &plds[w][l16][quad * 8];  // reads: +0, +32

  // ---- staging: running global pointers ----
  const int sr = tid >> 3;  // row 0..31 (+32 for second issue)
  const int sc = tid & 7;   // 16B chunk
  const int csoff = (sc ^ (sr & 7)) * 8;
  const unsigned short* kgrun = Kh + (size_t)sr * HEAD_D + csoff;
  const unsigned short* vgrun = Vh + (size_t)sr * T_SEQ + csoff;
  const int ntiles = qb / 64 + 1;

  // stage K tile 0
  load_lds16(kgrun, &Ks[0][w * 512]);
  load_lds16(kgrun + 2048, &Ks[0][(4 + w) * 512]);
  kgrun += 4096;

  for (int it = 0; it < ntiles; it++) {
    const int s0 = it * 64;
    const int cur = it & 1;
    const bool pref = (it + 1 < ntiles);  // block-uniform

    // barrier1: K[cur] staged (vmcnt(0) drains it); all waves' Vs reads of
    // the previous iteration completed before they reached this barrier.
    WAITCNT_VM0;
    block_barrier();

    // V first (consumed at barrier2), then K-next (consumed next iteration)
    load_lds16(vgrun, &Vs[w * 512]);
    load_lds16(vgrun + 32 * T_SEQ, &Vs[(4 + w) * 512]);
    vgrun += 64;
    if (pref) {
      unsigned short* kd = &Ks[cur ^ 1][w * 512];
      load_lds16(kgrun, kd);
      load_lds16(kgrun + 2048, kd + 2048);
      kgrun += 4096;
    }

    const unsigned short* ka = cur ? k1a : k0a;
    const unsigned short* kc = cur ? k1b : k0b;

    // S^T = K Q^T; D-layout: key = nt*16 + quad*4 + reg, q = l16.
    f32x4 sv[4];
#pragma unroll
    for (int nt = 0; nt < 4; nt++) {
      const bf16x8 a0 =
          __builtin_bit_cast(bf16x8, *(const int4*)(ka + nt * 1024));
      const bf16x8 a1 =
          __builtin_bit_cast(bf16x8, *(const int4*)(kc + nt * 1024));
      f32x4 z = (f32x4){0.f, 0.f, 0.f, 0.f};
      z = __builtin_amdgcn_mfma_f32_16x16x32_bf16(a0, bq[0], z, 0, 0, 0);
      sv[nt] = __builtin_amdgcn_mfma_f32_16x16x32_bf16(a1, bq[1], z, 0, 0, 0);
    }

    // causal mask: only the diagonal tile is partial
    if (s0 == qb) {
      const int qg = qw + l16;
#pragma unroll
      for (int nt = 0; nt < 4; nt++)
#pragma unroll
        for (int reg = 0; reg < 4; reg++) {
          const int sg = s0 + nt * 16 + quad * 4 + reg;
          if (sg > qg) sv[nt][reg] = -1e30f;
        }
    }

    // p = 2^s, pack 4 consecutive keys -> b64 LDS write (P^T layout [q][s])
#pragma unroll
    for (int nt = 0; nt < 4; nt++) {
      float p0 = exp2f(sv[nt][0]), p1 = exp2f(sv[nt][1]);
      float p2 = exp2f(sv[nt][2]), p3 = exp2f(sv[nt][3]);
      uint2 pk;
      pk.x = pack_bf16x2(p0, p1);
      pk.y = pack_bf16x2(p2, p3);
      *(uint2*)(pw + nt * 16) = pk;
    }

    // B-frags for PV: B[k=s][n=q]
    bf16x8 bp[2];
    bp[0] = __builtin_bit_cast(bf16x8, *(const int4*)(pr));
    bp[1] = __builtin_bit_cast(bf16x8, *(const int4*)(pr + 32));

    // lsum via MFMA (ones-A): D[m][q] = sum_k P^T[k][q]
    lacc = __builtin_amdgcn_mfma_f32_16x16x32_bf16(aones, bp[0], lacc, 0, 0, 0);
    lacc = __builtin_amdgcn_mfma_f32_16x16x32_bf16(aones, bp[1], lacc, 0, 0, 0);

    // barrier2: wait V-cur only (oldest 2 of 4) — K-next stays in flight.
    if (pref) {
      WAITCNT_VM2;
    } else {
      WAITCNT_VM0;
    }
    block_barrier();

    // O^T += V^T P^T
#pragma unroll
    for (int dt = 0; dt < 4; dt++) {
      const bf16x8 a0 =
          __builtin_bit_cast(bf16x8, *(const int4*)(va + dt * 1024));
      const bf16x8 a1 =
          __builtin_bit_cast(bf16x8, *(const int4*)(vb + dt * 1024));
      o[dt] = __builtin_amdgcn_mfma_f32_16x16x32_bf16(a0, bp[0], o[dt], 0, 0, 0);
      o[dt] = __builtin_amdgcn_mfma_f32_16x16x32_bf16(a1, bp[1], o[dt], 0, 0, 0);
    }
  }

  // epilogue: lacc holds full key-sum for q = l16 (replicated) -> no shuffles
  const float invl = 1.0f / lacc[0];
  const int row = qw + l16;
#pragma unroll
  for (int dt = 0; dt < 4; dt++) {
    uint2 pk;
    pk.x = pack_bf16x2(o[dt][0] * invl, o[dt][1] * invl);
    pk.y = pack_bf16x2(o[dt][2] * invl, o[dt][3] * invl);
    *(uint2*)(O + (size_t)row * C_DIM + h * HEAD_D + dt * 16 + quad * 4) = pk;
  }
}

// ---------------------------------------------------------------------------
// Launch (4 kernels: prep -> gemm_qkv_rope -> attn -> gemm_out)
// ---------------------------------------------------------------------------
extern "C" void kernel_launch(void* const* d_in, const int* in_sizes, int n_in,
                              void* d_out, int out_size, void* d_ws,
                              size_t ws_size, hipStream_t stream) {
  const float* x = (const float*)d_in[0];      // [T][C]
  const float* w_qkv = (const float*)d_in[1];  // [C][3C]
  const float* w_out = (const float*)d_in[2];  // [C][C]
  float* out = (float*)d_out;                  // [T][C]

  char* ws = (char*)d_ws;
  // Workspace layout (88 MB peak):
  //   [0, 8MB):   attn_ob bf16 [T][C]
  //   [24,25MB):  cs float2 [T][32] (RoPE cos/sin table)
  //   [48,56MB):  Qb bf16 [H][T][D] (roped, pre-scaled by 0.125*log2e)
  //   [56,64MB):  Kb bf16 [H][T][D] (roped)
  //   [64,72MB):  Vt bf16 [H][D][T] (written by gemm_qkv_rope epilogue)
  //   [72,80MB):  xb bf16 [T][C]
  //   [80,86MB):  wqkvT bf16 [3C][C]
  //   [86,88MB):  woutT bf16 [C][C]
  unsigned short* attn_ob = (unsigned short*)ws;
  float2* cst = (float2*)(ws + (size_t)24 * 1024 * 1024);
  unsigned short* Qb = (unsigned short*)(ws + (size_t)48 * 1024 * 1024);
  unsigned short* Kb = (unsigned short*)(ws + (size_t)56 * 1024 * 1024);
  unsigned short* Vt = (unsigned short*)(ws + (size_t)64 * 1024 * 1024);
  unsigned short* xb = (unsigned short*)(ws + (size_t)72 * 1024 * 1024);
  unsigned short* wqkvT = (unsigned short*)(ws + (size_t)80 * 1024 * 1024);
  unsigned short* woutT = (unsigned short*)(ws + (size_t)86 * 1024 * 1024);

  dim3 blk(256);

  // 0) fused cast + transposes + cos/sin table
  prep_inputs<<<dim3(3104), blk, 0, stream>>>(
      x, w_qkv, w_out, (unsigned int*)xb, (unsigned int*)wqkvT,
      (unsigned int*)woutT, cst);

  // 1) qkv projection with fused RoPE; Q->Qb, K->Kb, V->Vt directly
  gemm_qkv_rope<<<dim3(3072 / 128, T_SEQ / 128), blk, 0, stream>>>(
      xb, wqkvT, cst, Qb, Kb, Vt);

  // 2) flash attention (replay-validated protocol)
  attn_mfma<<<dim3(1024), blk, 0, stream>>>(Qb, Kb, Vt, attn_ob);

  // 3) out = attn_o @ w_out (64x64 tiles, BK=64, swizzled; 1024 blocks)
  gemm_bt_bf16_64<<<dim3(C_DIM / 64, T_SEQ / 64), blk, 0, stream>>>(
      attn_ob, woutT, out, T_SEQ, C_DIM, C_DIM);
}